// Round 8
// baseline (554.755 us; speedup 1.0000x reference)
//
#include <hip/hip_runtime.h>
#include <hip/hip_fp16.h>
#include <math.h>

#define F_IN 512
#define NHEAD1 8
#define NC1 8
#define F1 64      // NHEAD1 * NC1
#define NC2 16
#define NEG_SLOPE 0.2f
#define BSHIFT 7                 // bucket = dst >> 7 (128 dsts per bucket)
#define PART_G 512               // partition blocks
#define BUILD_CAP 4608           // LDS staging capacity per bucket

typedef _Float16 v8h __attribute__((ext_vector_type(8)));
typedef float v4f __attribute__((ext_vector_type(4)));

static __device__ __forceinline__ float leaky(float v) {
    return v > 0.0f ? v : NEG_SLOPE * v;
}

// ---- prep: W1T[c][k] = (fp16) W1[k][c]  (64 x 512, 64 KB) ----
__global__ __launch_bounds__(256) void k_prep(const float* __restrict__ W,
                                              _Float16* __restrict__ w1t) {
    int idx = blockIdx.x * 256 + threadIdx.x;
    if (idx < 64 * 512) {
        int c = idx >> 9, k = idx & 511;
        w1t[idx] = (_Float16)W[k * 64 + c];
    }
}

// ---- GEMM1 (MFMA fp16): h1[N,64] = x[N,512] @ W1[512,64] + fused logits ----
// 64x64 tile/block, 4 waves x (16 rows x 64 cols), K-step 64 (2 MFMA-k).
// A/B staged fp16 in LDS; accumulate fp32; h1 + logits stored fp32.
__global__ __launch_bounds__(256) void k_gemm1(const float* __restrict__ x,
                                               const _Float16* __restrict__ w1t,
                                               const float* __restrict__ a1s,
                                               const float* __restrict__ a1d,
                                               float* __restrict__ h1,
                                               float* __restrict__ al1s,
                                               float* __restrict__ al1d, int N) {
    __shared__ _Float16 xs[64][72];   // stride 72 halves = 144B (16B-aligned, ~2-way banks)
    __shared__ _Float16 ws[64][72];
    const int tid = threadIdx.x;
    const int lane = tid & 63;
    const int wv = tid >> 6;          // wave 0..3 -> rows 16wv..16wv+15
    const int row0 = blockIdx.x * 64;
    const int srow = tid >> 2;        // staging row (x) / col (w1t), 0..63
    const int skq = (tid & 3) * 16;   // staging k offset 0,16,32,48
    v4f acc[4] = {};                  // col-tiles 0..3 (cols 16*c4 .. +15)

    for (int k0 = 0; k0 < F_IN; k0 += 64) {
        // global loads for this K-step
        int gr = row0 + srow;
        float4 v0, v1, v2, v3;
        if (gr < N) {
            const float* p = x + (size_t)gr * F_IN + k0 + skq;
            v0 = *(const float4*)p;       v1 = *(const float4*)(p + 4);
            v2 = *(const float4*)(p + 8); v3 = *(const float4*)(p + 12);
        } else {
            v0 = make_float4(0.f, 0.f, 0.f, 0.f); v1 = v0; v2 = v0; v3 = v0;
        }
        const _Float16* q = w1t + (size_t)srow * F_IN + k0 + skq;
        v8h wa = *(const v8h*)q;
        v8h wb = *(const v8h*)(q + 8);
        v8h xa, xb;
        xa[0] = (_Float16)v0.x; xa[1] = (_Float16)v0.y;
        xa[2] = (_Float16)v0.z; xa[3] = (_Float16)v0.w;
        xa[4] = (_Float16)v1.x; xa[5] = (_Float16)v1.y;
        xa[6] = (_Float16)v1.z; xa[7] = (_Float16)v1.w;
        xb[0] = (_Float16)v2.x; xb[1] = (_Float16)v2.y;
        xb[2] = (_Float16)v2.z; xb[3] = (_Float16)v2.w;
        xb[4] = (_Float16)v3.x; xb[5] = (_Float16)v3.y;
        xb[6] = (_Float16)v3.z; xb[7] = (_Float16)v3.w;
        __syncthreads();              // previous iteration's MFMA reads done
        *(v8h*)&xs[srow][skq]     = xa;
        *(v8h*)&xs[srow][skq + 8] = xb;
        *(v8h*)&ws[srow][skq]     = wa;
        *(v8h*)&ws[srow][skq + 8] = wb;
        __syncthreads();
        #pragma unroll
        for (int kk = 0; kk < 64; kk += 32) {
            v8h a = *(const v8h*)&xs[wv * 16 + (lane & 15)][kk + (lane >> 4) * 8];
            #pragma unroll
            for (int c4 = 0; c4 < 4; ++c4) {
                v8h b = *(const v8h*)&ws[c4 * 16 + (lane & 15)][kk + (lane >> 4) * 8];
                acc[c4] = __builtin_amdgcn_mfma_f32_16x16x32_f16(a, b, acc[c4], 0, 0, 0);
            }
        }
    }
    // epilogue: C/D layout col=lane&15, row=(lane>>4)*4+reg (m89-verified)
    const int g = lane >> 4;
    const int cl = lane & 15;
    #pragma unroll
    for (int c4 = 0; c4 < 4; ++c4) {
        float asv = a1s[c4 * 16 + cl];   // flat [h][c] == flat[col]
        float adv = a1d[c4 * 16 + cl];
        #pragma unroll
        for (int r = 0; r < 4; ++r) {
            int gr = row0 + wv * 16 + g * 4 + r;
            float vacc = acc[c4][r];
            float ps = vacc * asv, pd = vacc * adv;
            ps += __shfl_xor(ps, 1); ps += __shfl_xor(ps, 2); ps += __shfl_xor(ps, 4);
            pd += __shfl_xor(pd, 1); pd += __shfl_xor(pd, 2); pd += __shfl_xor(pd, 4);
            if (gr < N) {
                h1[(size_t)gr * F1 + c4 * 16 + cl] = vacc;
                if ((lane & 7) == 0) {
                    int head = c4 * 2 + (cl >> 3);
                    al1s[gr * 8 + head] = ps;
                    al1d[gr * 8 + head] = pd;
                }
            }
        }
    }
}

// ================= bucketed CSR build (no global atomics) =================
__global__ __launch_bounds__(256) void k_bcount(const int* __restrict__ ei,
                                                int* __restrict__ counts,
                                                int E, int NBUCK, int chunk) {
    __shared__ int cnt[1024];
    const int g = blockIdx.x, tid = threadIdx.x;
    for (int i = tid; i < NBUCK; i += 256) cnt[i] = 0;
    __syncthreads();
    int lo = g * chunk, hi = lo + chunk;
    if (hi > E) hi = E;
    for (int e = lo + tid; e < hi; e += 256)
        atomicAdd(&cnt[ei[E + e] >> BSHIFT], 1);
    __syncthreads();
    for (int k = tid; k < NBUCK; k += 256)
        counts[k * PART_G + g] = cnt[k];   // bucket-major for the scan
}

__global__ __launch_bounds__(256) void k_scan_block(const int* __restrict__ in,
                                                    int* __restrict__ out,
                                                    int* __restrict__ blocksum, int L) {
    __shared__ int sdata[256];
    int t = threadIdx.x;
    int i = blockIdx.x * 256 + t;
    int v = (i < L) ? in[i] : 0;
    sdata[t] = v;
    __syncthreads();
    for (int off = 1; off < 256; off <<= 1) {
        int add = (t >= off) ? sdata[t - off] : 0;
        __syncthreads();
        sdata[t] += add;
        __syncthreads();
    }
    if (i < L) out[i] = sdata[t] - v;
    if (t == 255) blocksum[blockIdx.x] = sdata[t];
}

__global__ void k_scan_carry(const int* __restrict__ blocksum,
                             int* __restrict__ blockoffset, int NB) {
    int lane = threadIdx.x;   // 64 threads, 1 block
    int carry = 0;
    for (int base = 0; base < NB; base += 64) {
        int i = base + lane;
        int v = (i < NB) ? blocksum[i] : 0;
        int x = v;
        #pragma unroll
        for (int off = 1; off < 64; off <<= 1) {
            int y = __shfl_up(x, off);
            if (lane >= off) x += y;
        }
        if (i < NB) blockoffset[i] = carry + x - v;
        carry += __shfl(x, 63);
    }
}

// scatter packed ((dst&127)<<20 | src); block offsets folded in on the fly
__global__ __launch_bounds__(256) void k_bscatter(const int* __restrict__ ei,
                                                  const int* __restrict__ offs,
                                                  const int* __restrict__ boff,
                                                  unsigned* __restrict__ packed,
                                                  int E, int NBUCK, int chunk) {
    __shared__ int cur[1024];
    const int g = blockIdx.x, tid = threadIdx.x;
    for (int k = tid; k < NBUCK; k += 256) {
        int idx = k * PART_G + g;
        cur[k] = offs[idx] + boff[idx >> 8];
    }
    __syncthreads();
    int lo = g * chunk, hi = lo + chunk;
    if (hi > E) hi = E;
    for (int e = lo + tid; e < hi; e += 256) {
        int src = ei[e], dst = ei[E + e];
        int pos = atomicAdd(&cur[dst >> BSHIFT], 1);
        packed[pos] = ((unsigned)(dst & 127) << 20) | (unsigned)src;
    }
}

// one block per bucket -> exact CSR (rowptr + esrc), coalesced output
__global__ __launch_bounds__(256) void k_bbuild(const unsigned* __restrict__ packed,
                                                const int* __restrict__ offs,
                                                const int* __restrict__ boff,
                                                int* __restrict__ rowptr,
                                                int* __restrict__ esrc,
                                                int E, int N, int NBUCK) {
    __shared__ int sdeg[128], sinc[128], scur[128];
    __shared__ int sbuf[BUILD_CAP];
    const int k = blockIdx.x, tid = threadIdx.x;
    const int i0 = k * PART_G;
    const int s = offs[i0] + boff[i0 >> 8];
    int e;
    if (k + 1 < NBUCK) {
        int i1 = (k + 1) * PART_G;
        e = offs[i1] + boff[i1 >> 8];
    } else e = E;
    const int cnt = e - s;
    if (tid < 128) sdeg[tid] = 0;
    __syncthreads();
    for (int i = tid; i < cnt; i += 256)
        atomicAdd(&sdeg[packed[s + i] >> 20], 1);
    __syncthreads();
    if (tid < 128) sinc[tid] = sdeg[tid];
    __syncthreads();
    for (int off = 1; off < 128; off <<= 1) {
        int add = (tid < 128 && tid >= off) ? sinc[tid - off] : 0;
        __syncthreads();
        if (tid < 128) sinc[tid] += add;
        __syncthreads();
    }
    int nd = N - (k << BSHIFT);
    if (nd > 128) nd = 128;
    if (tid < nd) {
        int excl = sinc[tid] - sdeg[tid];
        rowptr[(k << BSHIFT) + tid] = s + excl;
        scur[tid] = excl;
    }
    if (k == 0 && tid == 0) rowptr[N] = E;
    __syncthreads();
    if (cnt <= BUILD_CAP) {
        for (int i = tid; i < cnt; i += 256) {
            unsigned p = packed[s + i];
            int pos = atomicAdd(&scur[p >> 20], 1);
            sbuf[pos] = (int)(p & 0xFFFFFu);
        }
        __syncthreads();
        for (int i = tid; i < cnt; i += 256) esrc[s + i] = sbuf[i];
    } else {
        for (int i = tid; i < cnt; i += 256) {
            unsigned p = packed[s + i];
            int pos = atomicAdd(&scur[p >> 20], 1);
            esrc[s + pos] = (int)(p & 0xFFFFFu);
        }
    }
}

// ---- layer-1 aggregation: wave/node, 4 edges in parallel (16 lanes/edge,
// float4 fp32 gather). src via DIRECT esrc load (16 lanes same addr -> L1
// broadcast) instead of wave-load + __shfl: removes the vmem->lgkm->vmem
// serial chain per iteration so gathers of all iterations pipeline.
__global__ __launch_bounds__(256) void k_agg1(
    const float* __restrict__ h1, const float* __restrict__ al1s,
    const float* __restrict__ al1d, const int* __restrict__ rowptr,
    const int* __restrict__ esrc, const float* __restrict__ b1,
    const float* __restrict__ W2, const float* __restrict__ a2s,
    const float* __restrict__ a2d, __half* __restrict__ h2h,
    float* __restrict__ al2s, float* __restrict__ al2d, int N) {
    const int lane = threadIdx.x & 63;
    const int wv = threadIdx.x >> 6;
    const int n = blockIdx.x * 4 + wv;
    if (n >= N) return;
    const int sub = lane >> 4;        // edge slot 0..3
    const int t = lane & 15;          // channels 4t..4t+3
    const int h = t >> 1;             // layer-1 head of these channels

    float4 w2r[4];
    #pragma unroll
    for (int j = 0; j < 4; ++j)
        w2r[j] = *(const float4*)(W2 + (4 * t + j) * NC2 + 4 * sub);
    const float4 b1v  = *(const float4*)(b1 + 4 * t);
    const float4 a2sv = *(const float4*)(a2s + 4 * sub);
    const float4 a2dv = *(const float4*)(a2d + 4 * sub);

    const float aldh = al1d[n * 8 + h];
    float s = 0.f, acc0 = 0.f, acc1 = 0.f, acc2 = 0.f, acc3 = 0.f;
    if (sub == 0) {   // self-loop
        float w0 = __expf(leaky(al1s[n * 8 + h] + aldh));
        float4 u = *(const float4*)(h1 + (size_t)n * F1 + t * 4);
        s = w0;
        acc0 = w0 * u.x; acc1 = w0 * u.y; acc2 = w0 * u.z; acc3 = w0 * u.w;
    }
    const int start = rowptr[n], end = rowptr[n + 1];
    for (int base = start; base < end; base += 64) {
        int cnt = end - base;
        if (cnt > 64) cnt = 64;
        for (int j4 = 0; j4 < cnt; j4 += 4) {
            int idx = j4 + sub;
            bool act = idx < cnt;
            int src = act ? esrc[base + idx] : 0;
            float w = act ? __expf(leaky(al1s[src * 8 + h] + aldh)) : 0.f;
            float4 u = *(const float4*)(h1 + (size_t)src * F1 + t * 4);
            s += w;
            acc0 = fmaf(w, u.x, acc0);
            acc1 = fmaf(w, u.y, acc1);
            acc2 = fmaf(w, u.z, acc2);
            acc3 = fmaf(w, u.w, acc3);
        }
    }
    // merge the 4 edge slots
    #pragma unroll
    for (int off = 16; off < 64; off <<= 1) {
        s    += __shfl_xor(s, off);
        acc0 += __shfl_xor(acc0, off);
        acc1 += __shfl_xor(acc1, off);
        acc2 += __shfl_xor(acc2, off);
        acc3 += __shfl_xor(acc3, off);
    }
    float rs = 1.0f / s;
    // ELU(x) = x>0 ? x : exp(x)-1  (abs err of __expf-1 vs expm1f ~1e-7)
    float v0 = acc0 * rs + b1v.x; v0 = v0 > 0.f ? v0 : __expf(v0) - 1.0f;
    float v1 = acc1 * rs + b1v.y; v1 = v1 > 0.f ? v1 : __expf(v1) - 1.0f;
    float v2 = acc2 * rs + b1v.z; v2 = v2 > 0.f ? v2 : __expf(v2) - 1.0f;
    float v3 = acc3 * rs + b1v.w; v3 = v3 > 0.f ? v3 : __expf(v3) - 1.0f;
    // fused gemm: cols 4sub..4sub+3, partial over channels 4t..4t+3
    float p0 = v0 * w2r[0].x + v1 * w2r[1].x + v2 * w2r[2].x + v3 * w2r[3].x;
    float p1 = v0 * w2r[0].y + v1 * w2r[1].y + v2 * w2r[2].y + v3 * w2r[3].y;
    float p2 = v0 * w2r[0].z + v1 * w2r[1].z + v2 * w2r[2].z + v3 * w2r[3].z;
    float p3 = v0 * w2r[0].w + v1 * w2r[1].w + v2 * w2r[2].w + v3 * w2r[3].w;
    #pragma unroll
    for (int off = 1; off < 16; off <<= 1) {
        p0 += __shfl_xor(p0, off);
        p1 += __shfl_xor(p1, off);
        p2 += __shfl_xor(p2, off);
        p3 += __shfl_xor(p3, off);
    }
    // layer-2 logits
    float ts = p0 * a2sv.x + p1 * a2sv.y + p2 * a2sv.z + p3 * a2sv.w;
    float td = p0 * a2dv.x + p1 * a2dv.y + p2 * a2dv.z + p3 * a2dv.w;
    ts += __shfl_xor(ts, 16); ts += __shfl_xor(ts, 32);
    td += __shfl_xor(td, 16); td += __shfl_xor(td, 32);
    if (t == 0) {
        union { __half2 h2v[2]; float2 f; } cv;
        cv.h2v[0] = __floats2half2_rn(p0, p1);
        cv.h2v[1] = __floats2half2_rn(p2, p3);
        *(float2*)(h2h + (size_t)n * NC2 + sub * 4) = cv.f;
    }
    if (lane == 0) { al2s[n] = ts; al2d[n] = td; }
}

// ---- layer-2 aggregation: 16 edges in parallel (4 lanes/edge, 8B fp16),
// direct esrc loads (no shfl), + bias + log-softmax (__logf), out fp32.
__global__ __launch_bounds__(256) void k_agg2(
    const __half* __restrict__ h2h, const float* __restrict__ al2s,
    const float* __restrict__ al2d, const int* __restrict__ rowptr,
    const int* __restrict__ esrc, const float* __restrict__ b2,
    float* __restrict__ out, int N) {
    const int lane = threadIdx.x & 63;
    const int wv = threadIdx.x >> 6;
    const int n = blockIdx.x * 4 + wv;
    if (n >= N) return;
    const int sub = lane >> 2;   // edge slot 0..15
    const int t = lane & 3;      // channels 4t..4t+3
    const float ald = al2d[n];
    float s = 0.f, a0 = 0.f, a1 = 0.f, a2 = 0.f, a3 = 0.f;
    if (sub == 0) {   // self-loop
        float w0 = __expf(leaky(al2s[n] + ald));
        float2 raw0 = *(const float2*)(h2h + (size_t)n * NC2 + 4 * t);
        const __half2* hp = (const __half2*)&raw0;
        float2 c01 = __half22float2(hp[0]);
        float2 c23 = __half22float2(hp[1]);
        s = w0;
        a0 = w0 * c01.x; a1 = w0 * c01.y;
        a2 = w0 * c23.x; a3 = w0 * c23.y;
    }
    const int start = rowptr[n], end = rowptr[n + 1];
    for (int base = start; base < end; base += 64) {
        int cnt = end - base;
        if (cnt > 64) cnt = 64;
        for (int j16 = 0; j16 < cnt; j16 += 16) {
            int idx = j16 + sub;
            bool act = idx < cnt;
            int src = act ? esrc[base + idx] : 0;
            float w = act ? __expf(leaky(al2s[src] + ald)) : 0.f;
            float2 raw = *(const float2*)(h2h + (size_t)src * NC2 + 4 * t);
            const __half2* hp = (const __half2*)&raw;
            float2 c01 = __half22float2(hp[0]);
            float2 c23 = __half22float2(hp[1]);
            s += w;
            a0 = fmaf(w, c01.x, a0);
            a1 = fmaf(w, c01.y, a1);
            a2 = fmaf(w, c23.x, a2);
            a3 = fmaf(w, c23.y, a3);
        }
    }
    #pragma unroll
    for (int off = 4; off < 64; off <<= 1) {
        s  += __shfl_xor(s, off);
        a0 += __shfl_xor(a0, off);
        a1 += __shfl_xor(a1, off);
        a2 += __shfl_xor(a2, off);
        a3 += __shfl_xor(a3, off);
    }
    float rs = 1.0f / s;
    const float4 b2v = *(const float4*)(b2 + 4 * t);
    float v0 = a0 * rs + b2v.x;
    float v1 = a1 * rs + b2v.y;
    float v2 = a2 * rs + b2v.z;
    float v3 = a3 * rs + b2v.w;
    float mm = fmaxf(fmaxf(v0, v1), fmaxf(v2, v3));
    #pragma unroll
    for (int off = 1; off < 4; off <<= 1) mm = fmaxf(mm, __shfl_xor(mm, off));
    float se = __expf(v0 - mm) + __expf(v1 - mm) + __expf(v2 - mm) + __expf(v3 - mm);
    #pragma unroll
    for (int off = 1; off < 4; off <<= 1) se += __shfl_xor(se, off);
    float l = __logf(se) + mm;
    if (sub == 0)
        *(float4*)(out + (size_t)n * NC2 + 4 * t) =
            make_float4(v0 - l, v1 - l, v2 - l, v3 - l);
}

extern "C" void kernel_launch(void* const* d_in, const int* in_sizes, int n_in,
                              void* d_out, int out_size, void* d_ws, size_t ws_size,
                              hipStream_t stream) {
    const float* x      = (const float*)d_in[0];
    const int*   ei     = (const int*)d_in[1];
    const float* W1     = (const float*)d_in[2];
    const float* a1_src = (const float*)d_in[3];
    const float* a1_dst = (const float*)d_in[4];
    const float* b1     = (const float*)d_in[5];
    const float* W2     = (const float*)d_in[6];
    const float* a2_src = (const float*)d_in[7];
    const float* a2_dst = (const float*)d_in[8];
    const float* b2     = (const float*)d_in[9];
    float* out = (float*)d_out;

    const int N = in_sizes[0] / F_IN;
    const int E = in_sizes[1] / 2;
    const int NH = N * NHEAD1;
    const int NBUCK = (N + 127) >> BSHIFT;
    const int L = NBUCK * PART_G;
    const int NB = (L + 255) / 256;
    const int chunk = (E + PART_G - 1) / PART_G;

    char* base = (char*)d_ws;
    size_t off = 0;
    auto alloc = [&](size_t bytes, size_t align) -> void* {
        off = (off + align - 1) & ~(align - 1);
        void* p = base + off; off += bytes; return p;
    };
    float* h1   = (float*)alloc((size_t)N * F1 * 4, 16);    // fp32 h1
    float* al1s = (float*)alloc((size_t)NH * 4, 16);
    float* al1d = (float*)alloc((size_t)NH * 4, 16);
    __half* h2h = (__half*)alloc((size_t)N * NC2 * 2, 16);  // fp16 h2
    float* al2s = (float*)alloc((size_t)N * 4, 16);
    float* al2d = (float*)alloc((size_t)N * 4, 16);
    int* rowptr = (int*)alloc((size_t)(N + 1) * 4, 16);
    int* esrc   = (int*)alloc((size_t)E * 4, 16);
    _Float16* w1t = (_Float16*)alloc((size_t)64 * F_IN * 2, 16);  // W1^T fp16
    // CSR temps overlay h1 (h1 written AFTER k_bbuild completes; same stream)
    // need E*4 + 2*L*4 + 2*NB*4 ~= 9.6MB <= N*F1*4 = 25.6MB
    char* tbase = (char*)h1;
    unsigned* packed = (unsigned*)tbase;                    // E * 4
    int* counts   = (int*)(tbase + (size_t)E * 4);          // L * 4
    int* offs     = counts + L;                             // L * 4
    int* blocksum = offs + L;                               // NB * 4
    int* boffset  = blocksum + NB;                          // NB * 4

    auto blocks = [](long long cnt, int b) { return (int)((cnt + b - 1) / b); };

    // ---- CSR build (bucketed: measured-good; direct atomic scatter was 140us
    // ---- due to 66B/4B write amplification — do not replace without profiling)
    k_bcount<<<PART_G, 256, 0, stream>>>(ei, counts, E, NBUCK, chunk);
    k_scan_block<<<NB, 256, 0, stream>>>(counts, offs, blocksum, L);
    k_scan_carry<<<1, 64, 0, stream>>>(blocksum, boffset, NB);
    k_bscatter<<<PART_G, 256, 0, stream>>>(ei, offs, boffset, packed, E, NBUCK, chunk);
    k_bbuild<<<NBUCK, 256, 0, stream>>>(packed, offs, boffset, rowptr, esrc, E, N, NBUCK);

    // ---- layer 1 (MFMA gemm + fused logits) ----
    k_prep<<<128, 256, 0, stream>>>(W1, w1t);
    k_gemm1<<<dim3((N + 63) / 64), dim3(256), 0, stream>>>(x, w1t, a1_src, a1_dst,
                                                           h1, al1s, al1d, N);
    k_agg1<<<blocks(N, 4), 256, 0, stream>>>(h1, al1s, al1d, rowptr, esrc,
                                             b1, W2, a2_src, a2_dst,
                                             h2h, al2s, al2d, N);
    // ---- layer 2 + log-softmax ----
    k_agg2<<<blocks(N, 4), 256, 0, stream>>>(h2h, al2s, al2d, rowptr, esrc, b2, out, N);
}

// Round 10
// 527.204 us; speedup vs baseline: 1.0523x; 1.0523x over previous
//
#include <hip/hip_runtime.h>
#include <hip/hip_fp16.h>
#include <math.h>

#define F_IN 512
#define NHEAD1 8
#define NC1 8
#define F1 64      // NHEAD1 * NC1
#define NC2 16
#define NEG_SLOPE 0.2f
#define BSHIFT 7                 // bucket = dst >> 7 (128 dsts per bucket)
#define PART_G 512               // partition blocks
#define BUILD_CAP 4608           // LDS staging capacity per bucket

typedef _Float16 v8h __attribute__((ext_vector_type(8)));
typedef float v4f __attribute__((ext_vector_type(4)));

static __device__ __forceinline__ float leaky(float v) {
    return v > 0.0f ? v : NEG_SLOPE * v;
}

// ---- prep: W1T[c][k] = (fp16) W1[k][c]  (64 x 512, 64 KB) ----
__global__ __launch_bounds__(256) void k_prep(const float* __restrict__ W,
                                              _Float16* __restrict__ w1t) {
    int idx = blockIdx.x * 256 + threadIdx.x;
    if (idx < 64 * 512) {
        int c = idx >> 9, k = idx & 511;
        w1t[idx] = (_Float16)W[k * 64 + c];
    }
}

// ---- GEMM1 (MFMA fp16): h1[N,64] = x[N,512] @ W1[512,64] + fused logits ----
__global__ __launch_bounds__(256) void k_gemm1(const float* __restrict__ x,
                                               const _Float16* __restrict__ w1t,
                                               const float* __restrict__ a1s,
                                               const float* __restrict__ a1d,
                                               float* __restrict__ h1,
                                               float* __restrict__ al1s,
                                               float* __restrict__ al1d, int N) {
    __shared__ _Float16 xs[64][72];   // stride 72 halves = 144B (16B-aligned, ~2-way banks)
    __shared__ _Float16 ws[64][72];
    const int tid = threadIdx.x;
    const int lane = tid & 63;
    const int wv = tid >> 6;          // wave 0..3 -> rows 16wv..16wv+15
    const int row0 = blockIdx.x * 64;
    const int srow = tid >> 2;        // staging row (x) / col (w1t), 0..63
    const int skq = (tid & 3) * 16;   // staging k offset 0,16,32,48
    v4f acc[4] = {};                  // col-tiles 0..3 (cols 16*c4 .. +15)

    for (int k0 = 0; k0 < F_IN; k0 += 64) {
        int gr = row0 + srow;
        float4 v0, v1, v2, v3;
        if (gr < N) {
            const float* p = x + (size_t)gr * F_IN + k0 + skq;
            v0 = *(const float4*)p;       v1 = *(const float4*)(p + 4);
            v2 = *(const float4*)(p + 8); v3 = *(const float4*)(p + 12);
        } else {
            v0 = make_float4(0.f, 0.f, 0.f, 0.f); v1 = v0; v2 = v0; v3 = v0;
        }
        const _Float16* q = w1t + (size_t)srow * F_IN + k0 + skq;
        v8h wa = *(const v8h*)q;
        v8h wb = *(const v8h*)(q + 8);
        v8h xa, xb;
        xa[0] = (_Float16)v0.x; xa[1] = (_Float16)v0.y;
        xa[2] = (_Float16)v0.z; xa[3] = (_Float16)v0.w;
        xa[4] = (_Float16)v1.x; xa[5] = (_Float16)v1.y;
        xa[6] = (_Float16)v1.z; xa[7] = (_Float16)v1.w;
        xb[0] = (_Float16)v2.x; xb[1] = (_Float16)v2.y;
        xb[2] = (_Float16)v2.z; xb[3] = (_Float16)v2.w;
        xb[4] = (_Float16)v3.x; xb[5] = (_Float16)v3.y;
        xb[6] = (_Float16)v3.z; xb[7] = (_Float16)v3.w;
        __syncthreads();              // previous iteration's MFMA reads done
        *(v8h*)&xs[srow][skq]     = xa;
        *(v8h*)&xs[srow][skq + 8] = xb;
        *(v8h*)&ws[srow][skq]     = wa;
        *(v8h*)&ws[srow][skq + 8] = wb;
        __syncthreads();
        #pragma unroll
        for (int kk = 0; kk < 64; kk += 32) {
            v8h a = *(const v8h*)&xs[wv * 16 + (lane & 15)][kk + (lane >> 4) * 8];
            #pragma unroll
            for (int c4 = 0; c4 < 4; ++c4) {
                v8h b = *(const v8h*)&ws[c4 * 16 + (lane & 15)][kk + (lane >> 4) * 8];
                acc[c4] = __builtin_amdgcn_mfma_f32_16x16x32_f16(a, b, acc[c4], 0, 0, 0);
            }
        }
    }
    // epilogue: C/D layout col=lane&15, row=(lane>>4)*4+reg (m89-verified)
    const int g = lane >> 4;
    const int cl = lane & 15;
    #pragma unroll
    for (int c4 = 0; c4 < 4; ++c4) {
        float asv = a1s[c4 * 16 + cl];   // flat [h][c] == flat[col]
        float adv = a1d[c4 * 16 + cl];
        #pragma unroll
        for (int r = 0; r < 4; ++r) {
            int gr = row0 + wv * 16 + g * 4 + r;
            float vacc = acc[c4][r];
            float ps = vacc * asv, pd = vacc * adv;
            ps += __shfl_xor(ps, 1); ps += __shfl_xor(ps, 2); ps += __shfl_xor(ps, 4);
            pd += __shfl_xor(pd, 1); pd += __shfl_xor(pd, 2); pd += __shfl_xor(pd, 4);
            if (gr < N) {
                h1[(size_t)gr * F1 + c4 * 16 + cl] = vacc;
                if ((lane & 7) == 0) {
                    int head = c4 * 2 + (cl >> 3);
                    al1s[gr * 8 + head] = ps;
                    al1d[gr * 8 + head] = pd;
                }
            }
        }
    }
}

// ================= bucketed CSR build (no global atomics) =================
__global__ __launch_bounds__(256) void k_bcount(const int* __restrict__ ei,
                                                int* __restrict__ counts,
                                                int E, int NBUCK, int chunk) {
    __shared__ int cnt[1024];
    const int g = blockIdx.x, tid = threadIdx.x;
    for (int i = tid; i < NBUCK; i += 256) cnt[i] = 0;
    __syncthreads();
    int lo = g * chunk, hi = lo + chunk;
    if (hi > E) hi = E;
    for (int e = lo + tid; e < hi; e += 256)
        atomicAdd(&cnt[ei[E + e] >> BSHIFT], 1);
    __syncthreads();
    for (int k = tid; k < NBUCK; k += 256)
        counts[k * PART_G + g] = cnt[k];   // bucket-major for the scan
}

__global__ __launch_bounds__(256) void k_scan_block(const int* __restrict__ in,
                                                    int* __restrict__ out,
                                                    int* __restrict__ blocksum, int L) {
    __shared__ int sdata[256];
    int t = threadIdx.x;
    int i = blockIdx.x * 256 + t;
    int v = (i < L) ? in[i] : 0;
    sdata[t] = v;
    __syncthreads();
    for (int off = 1; off < 256; off <<= 1) {
        int add = (t >= off) ? sdata[t - off] : 0;
        __syncthreads();
        sdata[t] += add;
        __syncthreads();
    }
    if (i < L) out[i] = sdata[t] - v;
    if (t == 255) blocksum[blockIdx.x] = sdata[t];
}

__global__ void k_scan_carry(const int* __restrict__ blocksum,
                             int* __restrict__ blockoffset, int NB) {
    int lane = threadIdx.x;   // 64 threads, 1 block
    int carry = 0;
    for (int base = 0; base < NB; base += 64) {
        int i = base + lane;
        int v = (i < NB) ? blocksum[i] : 0;
        int x = v;
        #pragma unroll
        for (int off = 1; off < 64; off <<= 1) {
            int y = __shfl_up(x, off);
            if (lane >= off) x += y;
        }
        if (i < NB) blockoffset[i] = carry + x - v;
        carry += __shfl(x, 63);
    }
}

// scatter packed ((dst&127)<<20 | src); block offsets folded in on the fly
__global__ __launch_bounds__(256) void k_bscatter(const int* __restrict__ ei,
                                                  const int* __restrict__ offs,
                                                  const int* __restrict__ boff,
                                                  unsigned* __restrict__ packed,
                                                  int E, int NBUCK, int chunk) {
    __shared__ int cur[1024];
    const int g = blockIdx.x, tid = threadIdx.x;
    for (int k = tid; k < NBUCK; k += 256) {
        int idx = k * PART_G + g;
        cur[k] = offs[idx] + boff[idx >> 8];
    }
    __syncthreads();
    int lo = g * chunk, hi = lo + chunk;
    if (hi > E) hi = E;
    for (int e = lo + tid; e < hi; e += 256) {
        int src = ei[e], dst = ei[E + e];
        int pos = atomicAdd(&cur[dst >> BSHIFT], 1);
        packed[pos] = ((unsigned)(dst & 127) << 20) | (unsigned)src;
    }
}

// one block per bucket -> exact CSR (rowptr + esrc), coalesced output
__global__ __launch_bounds__(256) void k_bbuild(const unsigned* __restrict__ packed,
                                                const int* __restrict__ offs,
                                                const int* __restrict__ boff,
                                                int* __restrict__ rowptr,
                                                int* __restrict__ esrc,
                                                int E, int N, int NBUCK) {
    __shared__ int sdeg[128], sinc[128], scur[128];
    __shared__ int sbuf[BUILD_CAP];
    const int k = blockIdx.x, tid = threadIdx.x;
    const int i0 = k * PART_G;
    const int s = offs[i0] + boff[i0 >> 8];
    int e;
    if (k + 1 < NBUCK) {
        int i1 = (k + 1) * PART_G;
        e = offs[i1] + boff[i1 >> 8];
    } else e = E;
    const int cnt = e - s;
    if (tid < 128) sdeg[tid] = 0;
    __syncthreads();
    for (int i = tid; i < cnt; i += 256)
        atomicAdd(&sdeg[packed[s + i] >> 20], 1);
    __syncthreads();
    if (tid < 128) sinc[tid] = sdeg[tid];
    __syncthreads();
    for (int off = 1; off < 128; off <<= 1) {
        int add = (tid < 128 && tid >= off) ? sinc[tid - off] : 0;
        __syncthreads();
        if (tid < 128) sinc[tid] += add;
        __syncthreads();
    }
    int nd = N - (k << BSHIFT);
    if (nd > 128) nd = 128;
    if (tid < nd) {
        int excl = sinc[tid] - sdeg[tid];
        rowptr[(k << BSHIFT) + tid] = s + excl;
        scur[tid] = excl;
    }
    if (k == 0 && tid == 0) rowptr[N] = E;
    __syncthreads();
    if (cnt <= BUILD_CAP) {
        for (int i = tid; i < cnt; i += 256) {
            unsigned p = packed[s + i];
            int pos = atomicAdd(&scur[p >> 20], 1);
            sbuf[pos] = (int)(p & 0xFFFFFu);
        }
        __syncthreads();
        for (int i = tid; i < cnt; i += 256) esrc[s + i] = sbuf[i];
    } else {
        for (int i = tid; i < cnt; i += 256) {
            unsigned p = packed[s + i];
            int pos = atomicAdd(&scur[p >> 20], 1);
            esrc[s + pos] = (int)(p & 0xFFFFFu);
        }
    }
}

// ---- layer-1 aggregation: wave/node, 4 edges in parallel (16 lanes/edge,
// float4 fp32 gather), msrc wave-load + shfl (r7-proven; direct esrc load
// regressed, r8). 2-deep software pipeline — iteration j+1's shfl + al1s +
// h1 loads issue BEFORE consuming iteration j, so the compiler can use a
// counted vmcnt and keep two gather rounds in flight (the per-iteration
// vmcnt(0) drain was the ~78us latency-serial component).
__global__ __launch_bounds__(256) void k_agg1(
    const float* __restrict__ h1, const float* __restrict__ al1s,
    const float* __restrict__ al1d, const int* __restrict__ rowptr,
    const int* __restrict__ esrc, const float* __restrict__ b1,
    const float* __restrict__ W2, const float* __restrict__ a2s,
    const float* __restrict__ a2d, __half* __restrict__ h2h,
    float* __restrict__ al2s, float* __restrict__ al2d, int N) {
    const int lane = threadIdx.x & 63;
    const int wv = threadIdx.x >> 6;
    const int n = blockIdx.x * 4 + wv;
    if (n >= N) return;
    const int sub = lane >> 4;        // edge slot 0..3
    const int t = lane & 15;          // channels 4t..4t+3
    const int h = t >> 1;             // layer-1 head of these channels

    float4 w2r[4];
    #pragma unroll
    for (int j = 0; j < 4; ++j)
        w2r[j] = *(const float4*)(W2 + (4 * t + j) * NC2 + 4 * sub);
    const float4 b1v  = *(const float4*)(b1 + 4 * t);
    const float4 a2sv = *(const float4*)(a2s + 4 * sub);
    const float4 a2dv = *(const float4*)(a2d + 4 * sub);

    const float aldh = al1d[n * 8 + h];
    float s = 0.f, acc0 = 0.f, acc1 = 0.f, acc2 = 0.f, acc3 = 0.f;
    if (sub == 0) {   // self-loop
        float w0 = __expf(leaky(al1s[n * 8 + h] + aldh));
        float4 u = *(const float4*)(h1 + (size_t)n * F1 + t * 4);
        s = w0;
        acc0 = w0 * u.x; acc1 = w0 * u.y; acc2 = w0 * u.z; acc3 = w0 * u.w;
    }
    const int start = rowptr[n], end = rowptr[n + 1];
    for (int base = start; base < end; base += 64) {
        int cnt = end - base;
        if (cnt > 64) cnt = 64;
        int msrc = (lane < cnt) ? esrc[base + lane] : 0;
        // pipeline prologue: stage edge slot (0+sub)
        bool act0 = sub < cnt;
        int src0 = __shfl(msrc, sub);
        float al0 = act0 ? al1s[src0 * 8 + h] : 0.f;
        float4 u0 = *(const float4*)(h1 + (size_t)src0 * F1 + t * 4);
        for (int j4 = 0; j4 < cnt; j4 += 4) {
            // stage next iteration's loads (independent of current consume)
            int idxn = j4 + 4 + sub;
            bool actn = idxn < cnt;
            int srcn = __shfl(msrc, idxn & 63);
            float aln = actn ? al1s[srcn * 8 + h] : 0.f;
            float4 un = *(const float4*)(h1 + (size_t)srcn * F1 + t * 4);
            // consume current
            float w = act0 ? __expf(leaky(al0 + aldh)) : 0.f;
            s += w;
            acc0 = fmaf(w, u0.x, acc0);
            acc1 = fmaf(w, u0.y, acc1);
            acc2 = fmaf(w, u0.z, acc2);
            acc3 = fmaf(w, u0.w, acc3);
            // rotate
            act0 = actn; al0 = aln; u0 = un;
        }
    }
    // merge the 4 edge slots
    #pragma unroll
    for (int off = 16; off < 64; off <<= 1) {
        s    += __shfl_xor(s, off);
        acc0 += __shfl_xor(acc0, off);
        acc1 += __shfl_xor(acc1, off);
        acc2 += __shfl_xor(acc2, off);
        acc3 += __shfl_xor(acc3, off);
    }
    float rs = 1.0f / s;
    // ELU(x) = x>0 ? x : exp(x)-1  (abs err of __expf-1 vs expm1f ~1e-7)
    float v0 = acc0 * rs + b1v.x; v0 = v0 > 0.f ? v0 : __expf(v0) - 1.0f;
    float v1 = acc1 * rs + b1v.y; v1 = v1 > 0.f ? v1 : __expf(v1) - 1.0f;
    float v2 = acc2 * rs + b1v.z; v2 = v2 > 0.f ? v2 : __expf(v2) - 1.0f;
    float v3 = acc3 * rs + b1v.w; v3 = v3 > 0.f ? v3 : __expf(v3) - 1.0f;
    // fused gemm: cols 4sub..4sub+3, partial over channels 4t..4t+3
    float p0 = v0 * w2r[0].x + v1 * w2r[1].x + v2 * w2r[2].x + v3 * w2r[3].x;
    float p1 = v0 * w2r[0].y + v1 * w2r[1].y + v2 * w2r[2].y + v3 * w2r[3].y;
    float p2 = v0 * w2r[0].z + v1 * w2r[1].z + v2 * w2r[2].z + v3 * w2r[3].z;
    float p3 = v0 * w2r[0].w + v1 * w2r[1].w + v2 * w2r[2].w + v3 * w2r[3].w;
    #pragma unroll
    for (int off = 1; off < 16; off <<= 1) {
        p0 += __shfl_xor(p0, off);
        p1 += __shfl_xor(p1, off);
        p2 += __shfl_xor(p2, off);
        p3 += __shfl_xor(p3, off);
    }
    // layer-2 logits
    float ts = p0 * a2sv.x + p1 * a2sv.y + p2 * a2sv.z + p3 * a2sv.w;
    float td = p0 * a2dv.x + p1 * a2dv.y + p2 * a2dv.z + p3 * a2dv.w;
    ts += __shfl_xor(ts, 16); ts += __shfl_xor(ts, 32);
    td += __shfl_xor(td, 16); td += __shfl_xor(td, 32);
    if (t == 0) {
        union { __half2 h2v[2]; float2 f; } cv;
        cv.h2v[0] = __floats2half2_rn(p0, p1);
        cv.h2v[1] = __floats2half2_rn(p2, p3);
        *(float2*)(h2h + (size_t)n * NC2 + sub * 4) = cv.f;
    }
    if (lane == 0) { al2s[n] = ts; al2d[n] = td; }
}

// ---- layer-2 aggregation (r7-proven shfl form): 16 edges in parallel
// (4 lanes/edge, 8B fp16); avg deg≈16 -> inner loop runs ~once, nothing to
// pipeline. + bias + log-softmax (__logf), writes d_out fp32.
__global__ __launch_bounds__(256) void k_agg2(
    const __half* __restrict__ h2h, const float* __restrict__ al2s,
    const float* __restrict__ al2d, const int* __restrict__ rowptr,
    const int* __restrict__ esrc, const float* __restrict__ b2,
    float* __restrict__ out, int N) {
    const int lane = threadIdx.x & 63;
    const int wv = threadIdx.x >> 6;
    const int n = blockIdx.x * 4 + wv;
    if (n >= N) return;
    const int sub = lane >> 2;   // edge slot 0..15
    const int t = lane & 3;      // channels 4t..4t+3
    const float ald = al2d[n];
    float s = 0.f, a0 = 0.f, a1 = 0.f, a2 = 0.f, a3 = 0.f;
    if (sub == 0) {   // self-loop
        float w0 = __expf(leaky(al2s[n] + ald));
        float2 raw0 = *(const float2*)(h2h + (size_t)n * NC2 + 4 * t);
        const __half2* hp = (const __half2*)&raw0;
        float2 c01 = __half22float2(hp[0]);
        float2 c23 = __half22float2(hp[1]);
        s = w0;
        a0 = w0 * c01.x; a1 = w0 * c01.y;
        a2 = w0 * c23.x; a3 = w0 * c23.y;
    }
    const int start = rowptr[n], end = rowptr[n + 1];
    for (int base = start; base < end; base += 64) {
        int cnt = end - base;
        if (cnt > 64) cnt = 64;
        int msrc = (lane < cnt) ? esrc[base + lane] : 0;
        for (int j16 = 0; j16 < cnt; j16 += 16) {
            int idx = j16 + sub;
            int src = __shfl(msrc, idx);
            float w = (idx < cnt) ? __expf(leaky(al2s[src] + ald)) : 0.f;
            float2 raw = *(const float2*)(h2h + (size_t)src * NC2 + 4 * t);
            const __half2* hp = (const __half2*)&raw;
            float2 c01 = __half22float2(hp[0]);
            float2 c23 = __half22float2(hp[1]);
            s += w;
            a0 = fmaf(w, c01.x, a0);
            a1 = fmaf(w, c01.y, a1);
            a2 = fmaf(w, c23.x, a2);
            a3 = fmaf(w, c23.y, a3);
        }
    }
    #pragma unroll
    for (int off = 4; off < 64; off <<= 1) {
        s  += __shfl_xor(s, off);
        a0 += __shfl_xor(a0, off);
        a1 += __shfl_xor(a1, off);
        a2 += __shfl_xor(a2, off);
        a3 += __shfl_xor(a3, off);
    }
    float rs = 1.0f / s;
    const float4 b2v = *(const float4*)(b2 + 4 * t);
    float v0 = a0 * rs + b2v.x;
    float v1 = a1 * rs + b2v.y;
    float v2 = a2 * rs + b2v.z;
    float v3 = a3 * rs + b2v.w;
    float mm = fmaxf(fmaxf(v0, v1), fmaxf(v2, v3));
    #pragma unroll
    for (int off = 1; off < 4; off <<= 1) mm = fmaxf(mm, __shfl_xor(mm, off));
    float se = __expf(v0 - mm) + __expf(v1 - mm) + __expf(v2 - mm) + __expf(v3 - mm);
    #pragma unroll
    for (int off = 1; off < 4; off <<= 1) se += __shfl_xor(se, off);
    float l = __logf(se) + mm;
    if (sub == 0)
        *(float4*)(out + (size_t)n * NC2 + 4 * t) =
            make_float4(v0 - l, v1 - l, v2 - l, v3 - l);
}

extern "C" void kernel_launch(void* const* d_in, const int* in_sizes, int n_in,
                              void* d_out, int out_size, void* d_ws, size_t ws_size,
                              hipStream_t stream) {
    const float* x      = (const float*)d_in[0];
    const int*   ei     = (const int*)d_in[1];
    const float* W1     = (const float*)d_in[2];
    const float* a1_src = (const float*)d_in[3];
    const float* a1_dst = (const float*)d_in[4];
    const float* b1     = (const float*)d_in[5];
    const float* W2     = (const float*)d_in[6];
    const float* a2_src = (const float*)d_in[7];
    const float* a2_dst = (const float*)d_in[8];
    const float* b2     = (const float*)d_in[9];
    float* out = (float*)d_out;

    const int N = in_sizes[0] / F_IN;
    const int E = in_sizes[1] / 2;
    const int NH = N * NHEAD1;
    const int NBUCK = (N + 127) >> BSHIFT;
    const int L = NBUCK * PART_G;
    const int NB = (L + 255) / 256;
    const int chunk = (E + PART_G - 1) / PART_G;

    char* base = (char*)d_ws;
    size_t off = 0;
    auto alloc = [&](size_t bytes, size_t align) -> void* {
        off = (off + align - 1) & ~(align - 1);
        void* p = base + off; off += bytes; return p;
    };
    float* h1   = (float*)alloc((size_t)N * F1 * 4, 16);    // fp32 h1
    float* al1s = (float*)alloc((size_t)NH * 4, 16);
    float* al1d = (float*)alloc((size_t)NH * 4, 16);
    __half* h2h = (__half*)alloc((size_t)N * NC2 * 2, 16);  // fp16 h2
    float* al2s = (float*)alloc((size_t)N * 4, 16);
    float* al2d = (float*)alloc((size_t)N * 4, 16);
    int* rowptr = (int*)alloc((size_t)(N + 1) * 4, 16);
    int* esrc   = (int*)alloc((size_t)E * 4, 16);
    _Float16* w1t = (_Float16*)alloc((size_t)64 * F_IN * 2, 16);  // W1^T fp16
    // CSR temps overlay h1 (h1 written AFTER k_bbuild completes; same stream)
    // need E*4 + 2*L*4 + 2*NB*4 ~= 9.6MB <= N*F1*4 = 25.6MB
    char* tbase = (char*)h1;
    unsigned* packed = (unsigned*)tbase;                    // E * 4
    int* counts   = (int*)(tbase + (size_t)E * 4);          // L * 4
    int* offs     = counts + L;                             // L * 4
    int* blocksum = offs + L;                               // NB * 4
    int* boffset  = blocksum + NB;                          // NB * 4

    auto blocks = [](long long cnt, int b) { return (int)((cnt + b - 1) / b); };

    // ---- CSR build (bucketed: measured-good; direct atomic scatter was 140us
    // ---- due to 66B/4B write amplification — do not replace without profiling)
    k_bcount<<<PART_G, 256, 0, stream>>>(ei, counts, E, NBUCK, chunk);
    k_scan_block<<<NB, 256, 0, stream>>>(counts, offs, blocksum, L);
    k_scan_carry<<<1, 64, 0, stream>>>(blocksum, boffset, NB);
    k_bscatter<<<PART_G, 256, 0, stream>>>(ei, offs, boffset, packed, E, NBUCK, chunk);
    k_bbuild<<<NBUCK, 256, 0, stream>>>(packed, offs, boffset, rowptr, esrc, E, N, NBUCK);

    // ---- layer 1 (MFMA gemm + fused logits) ----
    k_prep<<<128, 256, 0, stream>>>(W1, w1t);
    k_gemm1<<<dim3((N + 63) / 64), dim3(256), 0, stream>>>(x, w1t, a1_src, a1_dst,
                                                           h1, al1s, al1d, N);
    k_agg1<<<blocks(N, 4), 256, 0, stream>>>(h1, al1s, al1d, rowptr, esrc,
                                             b1, W2, a2_src, a2_dst,
                                             h2h, al2s, al2d, N);
    // ---- layer 2 + log-softmax ----
    k_agg2<<<blocks(N, 4), 256, 0, stream>>>(h2h, al2s, al2d, rowptr, esrc, b2, out, N);
}